// Round 5
// baseline (216.994 us; speedup 1.0000x reference)
//
#include <hip/hip_runtime.h>
#include <math.h>

// FFTConvReservoir: y = tanh(ifft(fft(u)*fft(K)).real + D*u); B=8,H=256,L=8192 fp32.
// Round 5: revert to two-kernel round-3 structure (fused round-4 regressed: kfft is
// only ~14.6us; fusion added 25% redundant K-FFT work). conv changes:
//  - kf spectrum prefetched into registers at kernel top (first use ~60% in) —
//    hides L2 latency that previously landed right after a barrier.
//  - passes B / merged-C / B' widened: both 16-elem groups loaded/computed/stored
//    together (shared twiddle pyramid) -> 2x independent LDS reads in flight.
//  - __launch_bounds__(256,2) pins VGPR <= 256 so occupancy stays 2 blocks/CU (LDS cap).

#define LL 8192
#define NT 256
#define HH 256
#define TWO_PI 6.2831853071795864f
#define CP16 0.98078528040323f   // cos(pi/16)
#define SP16 0.19509032201613f   // sin(pi/16)
#define CP8  0.92387953251129f   // cos(pi/8)
#define SP8  0.38268343236509f   // sin(pi/8)

__device__ __forceinline__ int PHYS(int i) {
    return i ^ ((i >> 5) & 15) ^ (((i >> 8) & 1) << 4);
}
__device__ __forceinline__ float fast_tanh(float x) {
    float e = __expf(2.0f * x);
    return 1.0f - 2.0f / (e + 1.0f);
}

// Twiddle pyramid: level j at offset (1<<j)-1, length 2^j.
template<int JT>
__device__ __forceinline__ void fill_pyr_cs(float c0, float s0, float Er, float Ei,
                                            float* twr, float* twi) {
    const int off = (1 << JT) - 1;
    twr[off] = c0; twi[off] = s0;
    #pragma unroll
    for (int m = 1; m < (1 << JT); ++m) {
        const float pr = twr[off + m - 1], pi = twi[off + m - 1];
        twr[off + m] = pr * Er - pi * Ei;
        twi[off + m] = pr * Ei + pi * Er;
    }
    #pragma unroll
    for (int j = JT - 1; j >= 0; --j) {
        #pragma unroll
        for (int m = 0; m < (1 << j); ++m) {
            const float a = twr[(2 << j) - 1 + m], b = twi[(2 << j) - 1 + m];
            twr[(1 << j) - 1 + m] = a * a - b * b;
            twi[(1 << j) - 1 + m] = 2.0f * a * b;
        }
    }
}
template<int JT>
__device__ __forceinline__ void fill_pyr(float ang0, float Er, float Ei,
                                         float* twr, float* twi) {
    float s, c;
    __sincosf(ang0, &s, &c);
    fill_pyr_cs<JT>(c, s, Er, Ei, twr, twi);
}

template<int R2>
__device__ __forceinline__ void dif_apply(float* xr, float* xi,
                                          const float* twr, const float* twi) {
    #pragma unroll
    for (int j = R2 - 1; j >= 0; --j) {
        #pragma unroll
        for (int q = 0; q < (1 << (R2 - 1)); ++q) {
            const int mm = q & ((1 << j) - 1);
            const int m0 = ((q >> j) << (j + 1)) | mm;
            const int m1 = m0 + (1 << j);
            const float wr = twr[(1 << j) - 1 + mm], wi = twi[(1 << j) - 1 + mm];
            const float ar = xr[m0], ai = xi[m0], br = xr[m1], bi = xi[m1];
            xr[m0] = ar + br; xi[m0] = ai + bi;
            const float dr = ar - br, di = ai - bi;
            xr[m1] = dr * wr - di * wi;
            xi[m1] = dr * wi + di * wr;
        }
    }
}
template<int R2>
__device__ __forceinline__ void dit_apply(float* xr, float* xi,
                                          const float* twr, const float* twi) {
    #pragma unroll
    for (int j = 0; j < R2; ++j) {
        #pragma unroll
        for (int q = 0; q < (1 << (R2 - 1)); ++q) {
            const int mm = q & ((1 << j) - 1);
            const int m0 = ((q >> j) << (j + 1)) | mm;
            const int m1 = m0 + (1 << j);
            const float wr = twr[(1 << j) - 1 + mm], wi = twi[(1 << j) - 1 + mm];
            const float br = xr[m1] * wr - xi[m1] * wi;
            const float bi = xr[m1] * wi + xi[m1] * wr;
            const float ar = xr[m0], ai = xi[m0];
            xr[m0] = ar + br; xi[m0] = ai + bi;
            xr[m1] = ar - br; xi[m1] = ai - bi;
        }
    }
}

// Fwd pass A (stages 12..8): xr/xi = natural elements [tid + 256m]; writes LDS.
__device__ __forceinline__ void fwd_A(float* xr, float* xi, int tid,
                                      float* re, float* im) {
    float twr[31], twi[31];
    fill_pyr<4>(-(TWO_PI / 8192.0f) * (float)tid, CP16, -SP16, twr, twi);
    dif_apply<5>(xr, xi, twr, twi);
    #pragma unroll
    for (int m = 0; m < 32; ++m) {
        const int p = PHYS(tid + (m << 8));
        re[p] = xr[m]; im[p] = xi[m];
    }
}

// Fwd pass B (stages 7..4), both groups wide; pyramid shared ((tid+256)&15 == tid&15).
__device__ __forceinline__ void fwd_B(int tid, float* re, float* im) {
    float xr[2][16], xi[2][16], twr[15], twi[15];
    #pragma unroll
    for (int gg = 0; gg < 2; ++gg) {
        const int g = tid + (gg << 8);
        const int base = ((g >> 4) << 8) | (g & 15);
        #pragma unroll
        for (int m = 0; m < 16; ++m) {
            const int p = PHYS(base + (m << 4));
            xr[gg][m] = re[p]; xi[gg][m] = im[p];
        }
    }
    fill_pyr<3>(-(TWO_PI / 256.0f) * (float)(tid & 15), CP8, -SP8, twr, twi);
    dif_apply<4>(xr[0], xi[0], twr, twi);
    dif_apply<4>(xr[1], xi[1], twr, twi);
    #pragma unroll
    for (int gg = 0; gg < 2; ++gg) {
        const int g = tid + (gg << 8);
        const int base = ((g >> 4) << 8) | (g & 15);
        #pragma unroll
        for (int m = 0; m < 16; ++m) {
            const int p = PHYS(base + (m << 4));
            re[p] = xr[gg][m]; im[p] = xi[gg][m];
        }
    }
}

// Inv pass B' (stages 4..7, conjugate twiddles), both groups wide.
__device__ __forceinline__ void inv_B(int tid, float* re, float* im) {
    float xr[2][16], xi[2][16], twr[15], twi[15];
    #pragma unroll
    for (int gg = 0; gg < 2; ++gg) {
        const int g = tid + (gg << 8);
        const int base = ((g >> 4) << 8) | (g & 15);
        #pragma unroll
        for (int m = 0; m < 16; ++m) {
            const int p = PHYS(base + (m << 4));
            xr[gg][m] = re[p]; xi[gg][m] = im[p];
        }
    }
    fill_pyr<3>((TWO_PI / 256.0f) * (float)(tid & 15), CP8, SP8, twr, twi);
    dit_apply<4>(xr[0], xi[0], twr, twi);
    dit_apply<4>(xr[1], xi[1], twr, twi);
    #pragma unroll
    for (int gg = 0; gg < 2; ++gg) {
        const int g = tid + (gg << 8);
        const int base = ((g >> 4) << 8) | (g & 15);
        #pragma unroll
        for (int m = 0; m < 16; ++m) {
            const int p = PHYS(base + (m << 4));
            re[p] = xr[gg][m]; im[p] = xi[gg][m];
        }
    }
}

__global__ __launch_bounds__(NT) void kfft_kernel(const float* __restrict__ K,
                                                  float2* __restrict__ Kf) {
    __shared__ float re[LL];
    __shared__ float im[LL];
    const int h = blockIdx.x;
    const int tid = threadIdx.x;
    const float* Kr = K + (size_t)h * LL;
    float xr[32], xi[32];
    #pragma unroll
    for (int m = 0; m < 32; ++m) {
        xr[m] = Kr[tid + (m << 8)];
        xi[m] = 0.0f;
    }
    fwd_A(xr, xi, tid, re, im);
    __syncthreads();
    fwd_B(tid, re, im);
    __syncthreads();
    // Plain fwd pass C (stages 3..0, constant twiddles).
    #pragma unroll
    for (int gg = 0; gg < 2; ++gg) {
        const int base = (tid + (gg << 8)) << 4;
        float yr[16], yi[16], twr[15], twi[15];
        #pragma unroll
        for (int m = 0; m < 16; ++m) {
            const int p = PHYS(base + m);
            yr[m] = re[p]; yi[m] = im[p];
        }
        fill_pyr_cs<3>(1.0f, 0.0f, CP8, -SP8, twr, twi);
        dif_apply<4>(yr, yi, twr, twi);
        #pragma unroll
        for (int m = 0; m < 16; ++m) {
            const int p = PHYS(base + m);
            re[p] = yr[m]; im[p] = yi[m];
        }
    }
    __syncthreads();
    // Store spectrum in storage order, laid out [m*512 + i0] to match conv's
    // merged-C register pass (coalesced float2 writes; LDS reads 2-way free).
    float2* outp = Kf + (size_t)h * LL;
    #pragma unroll
    for (int t = 0; t < 32; ++t) {
        const int lin = t * NT + tid;
        const int m = lin >> 9;
        const int i0 = lin & 511;
        const int p = PHYS((i0 << 4) | m);
        outp[lin] = make_float2(re[p], im[p]);
    }
}

__global__ __launch_bounds__(NT, 2) void conv_kernel(const float* __restrict__ u,
                                                     const float2* __restrict__ Kf,
                                                     const float* __restrict__ D,
                                                     float* __restrict__ out) {
    __shared__ float re[LL];
    __shared__ float im[LL];
    const int tid = threadIdx.x;
    const int h = blockIdx.x & (HH - 1);
    const int pr_ = blockIdx.x >> 8;        // batch pair 0..3
    const size_t off0 = ((size_t)(pr_ * 2) * HH + h) * LL;
    const size_t off1 = off0 + (size_t)HH * LL;
    const float* u0 = u + off0;
    const float* u1 = u + off1;

    // u loads first (consumed by fwd_A), then kf prefetch (consumed in merged C,
    // ~60% into the kernel -> latency fully hidden behind fwd A/B).
    float xr[32], xi[32];
    #pragma unroll
    for (int m = 0; m < 32; ++m) {
        xr[m] = u0[tid + (m << 8)];
        xi[m] = u1[tid + (m << 8)];
    }
    const float2* kf = Kf + (size_t)h * LL;
    float kfr[2][16], kfi[2][16];
    #pragma unroll
    for (int gg = 0; gg < 2; ++gg) {
        const int i0 = tid + (gg << 8);
        #pragma unroll
        for (int m = 0; m < 16; ++m) {
            const float2 w = kf[(m << 9) + i0];
            kfr[gg][m] = w.x; kfi[gg][m] = w.y;
        }
    }

    fwd_A(xr, xi, tid, re, im);       // z = u0 + i*u1
    __syncthreads();
    fwd_B(tid, re, im);
    __syncthreads();

    // Merged pass C (wide): fwd stages 3..0, pointwise * kf, inv stages 0..3.
    {
        float yr[2][16], yi[2][16], twr[15], twi[15];
        #pragma unroll
        for (int gg = 0; gg < 2; ++gg) {
            const int base = (tid + (gg << 8)) << 4;
            #pragma unroll
            for (int m = 0; m < 16; ++m) {
                const int p = PHYS(base + m);
                yr[gg][m] = re[p]; yi[gg][m] = im[p];
            }
        }
        fill_pyr_cs<3>(1.0f, 0.0f, CP8, -SP8, twr, twi);
        dif_apply<4>(yr[0], yi[0], twr, twi);
        dif_apply<4>(yr[1], yi[1], twr, twi);
        #pragma unroll
        for (int gg = 0; gg < 2; ++gg) {
            #pragma unroll
            for (int m = 0; m < 16; ++m) {
                const float a = yr[gg][m], b = yi[gg][m];
                yr[gg][m] = a * kfr[gg][m] - b * kfi[gg][m];
                yi[gg][m] = a * kfi[gg][m] + b * kfr[gg][m];
            }
        }
        fill_pyr_cs<3>(1.0f, 0.0f, CP8, SP8, twr, twi);
        dit_apply<4>(yr[0], yi[0], twr, twi);
        dit_apply<4>(yr[1], yi[1], twr, twi);
        #pragma unroll
        for (int gg = 0; gg < 2; ++gg) {
            const int base = (tid + (gg << 8)) << 4;
            #pragma unroll
            for (int m = 0; m < 16; ++m) {
                const int p = PHYS(base + m);
                re[p] = yr[gg][m]; im[p] = yi[gg][m];
            }
        }
    }
    __syncthreads();

    inv_B(tid, re, im);
    __syncthreads();

    // Inv pass A' (stages 8..12) + fused epilogue.
    {
        float twr[31], twi[31];
        #pragma unroll
        for (int m = 0; m < 32; ++m) {
            const int p = PHYS(tid + (m << 8));
            xr[m] = re[p]; xi[m] = im[p];
        }
        fill_pyr<4>((TWO_PI / 8192.0f) * (float)tid, CP16, SP16, twr, twi);
        dit_apply<5>(xr, xi, twr, twi);
    }
    // xr[m] = L*y0[tid+256m], xi[m] = L*y1[tid+256m]; kfft folded (Kf+D)/N? No —
    // round-3 semantics: kf is raw FFT(K); apply invN and skip here.
    const float dh = D[h];
    const float invN = 1.0f / (float)LL;
    float* o0 = out + off0;
    float* o1 = out + off1;
    #pragma unroll
    for (int m = 0; m < 32; ++m) {
        const int n = tid + (m << 8);
        o0[n] = fast_tanh(xr[m] * invN + dh * u0[n]);
        o1[n] = fast_tanh(xi[m] * invN + dh * u1[n]);
    }
}

extern "C" void kernel_launch(void* const* d_in, const int* in_sizes, int n_in,
                              void* d_out, int out_size, void* d_ws, size_t ws_size,
                              hipStream_t stream) {
    const float* u = (const float*)d_in[0];   // (8, 256, 8192)
    const float* K = (const float*)d_in[1];   // (256, 8192)
    const float* D = (const float*)d_in[2];   // (256,)
    float* out = (float*)d_out;               // (8, 256, 8192)
    float2* Kf = (float2*)d_ws;               // 256 * 8192 float2 = 16 MB

    kfft_kernel<<<dim3(HH), dim3(NT), 0, stream>>>(K, Kf);
    conv_kernel<<<dim3(4 * HH), dim3(NT), 0, stream>>>(u, Kf, D, out);
}

// Round 6
// 160.520 us; speedup vs baseline: 1.3518x; 1.3518x over previous
//
#include <hip/hip_runtime.h>
#include <math.h>

// FFTConvReservoir: y = tanh(ifft(fft(u)*fft(K)).real + D*u); B=8,H=256,L=8192 fp32.
// Round 6: 512-thread blocks (same 64KB LDS -> 16 waves/CU instead of 8).
// 13 stages = A(12..9) | B(8..5) | C(4..1) + shfl stage0 + mult + shfl inv-stage0 +
// C'(1..4) | B'(5..8) | A'(9..12). Stage-0 pairs (2m,2m+1) live in adjacent lanes
// (tid=2d+par) -> __shfl_xor lane 1, no extra LDS pass.
// kw = (FFT(K)+D)/N folded in kfft -> conv epilogue is tanh only, u read once.
// Swizzle PHYS extended with i[5] in bit4: all three pass patterns exactly 2-way (free).
// Lesson (R5): no __launch_bounds__ min-occupancy arg — it forced a 128-VGPR cap + spills.

#define LL 8192
#define NT 512
#define HH 256
#define TWO_PI 6.2831853071795864f
#define CP8  0.92387953251129f   // cos(pi/8)  = cos(2pi/16)
#define SP8  0.38268343236509f   // sin(pi/8)

__device__ __forceinline__ int PHYS(int i) {
    return i ^ ((i >> 5) & 15) ^ ((((i >> 8) ^ (i >> 5)) & 1) << 4);
}
__device__ __forceinline__ float fast_tanh(float x) {
    float e = __expf(2.0f * x);
    return 1.0f - 2.0f / (e + 1.0f);
}

// Twiddle pyramid: level j at offset (1<<j)-1, length 2^j; top level chained cmul,
// lower levels by squaring (angle doubling).
template<int JT>
__device__ __forceinline__ void fill_pyr_cs(float c0, float s0, float Er, float Ei,
                                            float* twr, float* twi) {
    const int off = (1 << JT) - 1;
    twr[off] = c0; twi[off] = s0;
    #pragma unroll
    for (int m = 1; m < (1 << JT); ++m) {
        const float pr = twr[off + m - 1], pi = twi[off + m - 1];
        twr[off + m] = pr * Er - pi * Ei;
        twi[off + m] = pr * Ei + pi * Er;
    }
    #pragma unroll
    for (int j = JT - 1; j >= 0; --j) {
        #pragma unroll
        for (int m = 0; m < (1 << j); ++m) {
            const float a = twr[(2 << j) - 1 + m], b = twi[(2 << j) - 1 + m];
            twr[(1 << j) - 1 + m] = a * a - b * b;
            twi[(1 << j) - 1 + m] = 2.0f * a * b;
        }
    }
}
template<int JT>
__device__ __forceinline__ void fill_pyr(float ang0, float Er, float Ei,
                                         float* twr, float* twi) {
    float s, c;
    __sincosf(ang0, &s, &c);
    fill_pyr_cs<JT>(c, s, Er, Ei, twr, twi);
}

template<int R2>
__device__ __forceinline__ void dif_apply(float* xr, float* xi,
                                          const float* twr, const float* twi) {
    #pragma unroll
    for (int j = R2 - 1; j >= 0; --j) {
        #pragma unroll
        for (int q = 0; q < (1 << (R2 - 1)); ++q) {
            const int mm = q & ((1 << j) - 1);
            const int m0 = ((q >> j) << (j + 1)) | mm;
            const int m1 = m0 + (1 << j);
            const float wr = twr[(1 << j) - 1 + mm], wi = twi[(1 << j) - 1 + mm];
            const float ar = xr[m0], ai = xi[m0], br = xr[m1], bi = xi[m1];
            xr[m0] = ar + br; xi[m0] = ai + bi;
            const float dr = ar - br, di = ai - bi;
            xr[m1] = dr * wr - di * wi;
            xi[m1] = dr * wi + di * wr;
        }
    }
}
template<int R2>
__device__ __forceinline__ void dit_apply(float* xr, float* xi,
                                          const float* twr, const float* twi) {
    #pragma unroll
    for (int j = 0; j < R2; ++j) {
        #pragma unroll
        for (int q = 0; q < (1 << (R2 - 1)); ++q) {
            const int mm = q & ((1 << j) - 1);
            const int m0 = ((q >> j) << (j + 1)) | mm;
            const int m1 = m0 + (1 << j);
            const float wr = twr[(1 << j) - 1 + mm], wi = twi[(1 << j) - 1 + mm];
            const float br = xr[m1] * wr - xi[m1] * wi;
            const float bi = xr[m1] * wi + xi[m1] * wr;
            const float ar = xr[m0], ai = xi[m0];
            xr[m0] = ar + br; xi[m0] = ai + bi;
            xr[m1] = ar - br; xi[m1] = ai - bi;
        }
    }
}

// Pass A fwd (stages 12..9): xr/xi = natural elements [tid + 512m]; writes LDS.
__device__ __forceinline__ void fwd_A(float* xr, float* xi, int tid,
                                      float* re, float* im) {
    float twr[15], twi[15];
    fill_pyr<3>(-(TWO_PI / 8192.0f) * (float)tid, CP8, -SP8, twr, twi);
    dif_apply<4>(xr, xi, twr, twi);
    #pragma unroll
    for (int m = 0; m < 16; ++m) {
        const int p = PHYS(tid + (m << 9));
        re[p] = xr[m]; im[p] = xi[m];
    }
}
// Pass B fwd (stages 8..5): p = 512c + r + 32m, c=tid>>5, r=tid&31.
__device__ __forceinline__ void fwd_B(int tid, float* re, float* im) {
    const int r_ = tid & 31;
    const int base = ((tid >> 5) << 9) | r_;
    float xr[16], xi[16], twr[15], twi[15];
    #pragma unroll
    for (int m = 0; m < 16; ++m) {
        const int p = PHYS(base + (m << 5));
        xr[m] = re[p]; xi[m] = im[p];
    }
    fill_pyr<3>(-(TWO_PI / 512.0f) * (float)r_, CP8, -SP8, twr, twi);
    dif_apply<4>(xr, xi, twr, twi);
    #pragma unroll
    for (int m = 0; m < 16; ++m) {
        const int p = PHYS(base + (m << 5));
        re[p] = xr[m]; im[p] = xi[m];
    }
}
// Pass B inv (stages 5..8, conjugate twiddles).
__device__ __forceinline__ void inv_B(int tid, float* re, float* im) {
    const int r_ = tid & 31;
    const int base = ((tid >> 5) << 9) | r_;
    float xr[16], xi[16], twr[15], twi[15];
    #pragma unroll
    for (int m = 0; m < 16; ++m) {
        const int p = PHYS(base + (m << 5));
        xr[m] = re[p]; xi[m] = im[p];
    }
    fill_pyr<3>((TWO_PI / 512.0f) * (float)r_, CP8, SP8, twr, twi);
    dit_apply<4>(xr, xi, twr, twi);
    #pragma unroll
    for (int m = 0; m < 16; ++m) {
        const int p = PHYS(base + (m << 5));
        re[p] = xr[m]; im[p] = xi[m];
    }
}

__global__ __launch_bounds__(NT) void kfft_kernel(const float* __restrict__ K,
                                                  const float* __restrict__ D,
                                                  float2* __restrict__ Kf) {
    __shared__ float re[LL];
    __shared__ float im[LL];
    const int h = blockIdx.x;
    const int tid = threadIdx.x;
    const float* Kr = K + (size_t)h * LL;
    float xr[16], xi[16];
    #pragma unroll
    for (int m = 0; m < 16; ++m) {
        xr[m] = Kr[tid + (m << 9)];
        xi[m] = 0.0f;
    }
    fwd_A(xr, xi, tid, re, im);
    __syncthreads();
    fwd_B(tid, re, im);
    __syncthreads();
    // Pass C (stages 4..1) + shfl stage 0; fold kw = (X + D[h]) / N; store.
    const int par = tid & 1;
    const int base = ((tid >> 1) << 5) | par;
    float yr[16], yi[16], twr[15], twi[15];
    #pragma unroll
    for (int m = 0; m < 16; ++m) {
        const int p = PHYS(base + (m << 1));
        yr[m] = re[p]; yi[m] = im[p];
    }
    fill_pyr<3>(-(TWO_PI / 32.0f) * (float)par, CP8, -SP8, twr, twi);
    dif_apply<4>(yr, yi, twr, twi);
    const float dh = D[h];
    const float invN = 1.0f / (float)LL;
    float2* outp = Kf + (size_t)h * LL;
    #pragma unroll
    for (int m = 0; m < 16; ++m) {
        const float ar = yr[m], ai = yi[m];
        const float br = __shfl_xor(ar, 1), bi = __shfl_xor(ai, 1);
        const float sr = par ? (br - ar) : (ar + br);   // fwd stage-0
        const float si = par ? (bi - ai) : (ai + bi);
        outp[(m << 9) + tid] = make_float2((sr + dh) * invN, si * invN);
    }
}

__global__ __launch_bounds__(NT) void conv_kernel(const float* __restrict__ u,
                                                  const float2* __restrict__ Kf,
                                                  float* __restrict__ out) {
    __shared__ float re[LL];
    __shared__ float im[LL];
    const int tid = threadIdx.x;
    const int h = blockIdx.x & (HH - 1);
    const int pr_ = blockIdx.x >> 8;        // batch pair 0..3
    const size_t off0 = ((size_t)(pr_ * 2) * HH + h) * LL;
    const size_t off1 = off0 + (size_t)HH * LL;
    const float* u0 = u + off0;
    const float* u1 = u + off1;

    float xr[16], xi[16];
    #pragma unroll
    for (int m = 0; m < 16; ++m) {
        xr[m] = u0[tid + (m << 9)];
        xi[m] = u1[tid + (m << 9)];
    }
    fwd_A(xr, xi, tid, re, im);       // z = u0 + i*u1
    __syncthreads();
    fwd_B(tid, re, im);
    __syncthreads();

    // Merged pass C: stages 4..1, shfl stage0, * kw, shfl inv-stage0, stages 1..4.
    {
        const int par = tid & 1;
        const int base = ((tid >> 1) << 5) | par;
        const float2* kf = Kf + (size_t)h * LL;
        float kwr[16], kwi[16];
        #pragma unroll
        for (int m = 0; m < 16; ++m) {       // issue early; consumed after dif_apply
            const float2 w = kf[(m << 9) + tid];
            kwr[m] = w.x; kwi[m] = w.y;
        }
        float yr[16], yi[16], twr[15], twi[15];
        #pragma unroll
        for (int m = 0; m < 16; ++m) {
            const int p = PHYS(base + (m << 1));
            yr[m] = re[p]; yi[m] = im[p];
        }
        fill_pyr<3>(-(TWO_PI / 32.0f) * (float)par, CP8, -SP8, twr, twi);
        dif_apply<4>(yr, yi, twr, twi);
        #pragma unroll
        for (int m = 0; m < 16; ++m) {
            const float ar = yr[m], ai = yi[m];
            const float br = __shfl_xor(ar, 1), bi = __shfl_xor(ai, 1);
            const float sr = par ? (br - ar) : (ar + br);   // fwd stage-0
            const float si = par ? (bi - ai) : (ai + bi);
            const float mr = sr * kwr[m] - si * kwi[m];     // pointwise * kw
            const float mi = sr * kwi[m] + si * kwr[m];
            const float qr = __shfl_xor(mr, 1), qi = __shfl_xor(mi, 1);
            yr[m] = par ? (qr - mr) : (mr + qr);            // inv stage-0
            yi[m] = par ? (qi - mi) : (mi + qi);
        }
        fill_pyr<3>((TWO_PI / 32.0f) * (float)par, CP8, SP8, twr, twi);
        dit_apply<4>(yr, yi, twr, twi);
        #pragma unroll
        for (int m = 0; m < 16; ++m) {
            const int p = PHYS(base + (m << 1));
            re[p] = yr[m]; im[p] = yi[m];
        }
    }
    __syncthreads();

    inv_B(tid, re, im);
    __syncthreads();

    // Pass A inv (stages 9..12) + epilogue (skip/norm already folded into kw).
    {
        float twr[15], twi[15];
        #pragma unroll
        for (int m = 0; m < 16; ++m) {
            const int p = PHYS(tid + (m << 9));
            xr[m] = re[p]; xi[m] = im[p];
        }
        fill_pyr<3>((TWO_PI / 8192.0f) * (float)tid, CP8, SP8, twr, twi);
        dit_apply<4>(xr, xi, twr, twi);
    }
    float* o0 = out + off0;
    float* o1 = out + off1;
    #pragma unroll
    for (int m = 0; m < 16; ++m) {
        const int n = tid + (m << 9);
        o0[n] = fast_tanh(xr[m]);
        o1[n] = fast_tanh(xi[m]);
    }
}

extern "C" void kernel_launch(void* const* d_in, const int* in_sizes, int n_in,
                              void* d_out, int out_size, void* d_ws, size_t ws_size,
                              hipStream_t stream) {
    const float* u = (const float*)d_in[0];   // (8, 256, 8192)
    const float* K = (const float*)d_in[1];   // (256, 8192)
    const float* D = (const float*)d_in[2];   // (256,)
    float* out = (float*)d_out;               // (8, 256, 8192)
    float2* Kf = (float2*)d_ws;               // 256 * 8192 float2 = 16 MB

    kfft_kernel<<<dim3(HH), dim3(NT), 0, stream>>>(K, D, Kf);
    conv_kernel<<<dim3(4 * HH), dim3(NT), 0, stream>>>(u, Kf, out);
}